// Round 9
// baseline (244.354 us; speedup 1.0000x reference)
//
#include <hip/hip_runtime.h>
#include <hip/hip_bf16.h>
#include <math.h>

#define SEQ 2048
#define DM 1024
#define NH 16
#define DKV 64
#define MTOT 4096   /* BATCH*SEQ */
#define PSTR 40     /* P-tile LDS row stride in shorts */

typedef __attribute__((ext_vector_type(8))) short bf16x8;
typedef __attribute__((ext_vector_type(4))) short s16x4;
typedef __attribute__((ext_vector_type(4))) float f32x4;
typedef unsigned short ushort_t;

__device__ __forceinline__ short f2bf(float f) {
    union { float f; unsigned u; } v; v.f = f;
    unsigned r = v.u + 0x7fffu + ((v.u >> 16) & 1u);
    return (short)(r >> 16);
}

__device__ __forceinline__ bf16x8 cvt8(f32x4 a, f32x4 b) {
    union { __hip_bfloat162 h[4]; bf16x8 v; } u;
    u.h[0] = __float22bfloat162_rn(float2{a[0], a[1]});
    u.h[1] = __float22bfloat162_rn(float2{a[2], a[3]});
    u.h[2] = __float22bfloat162_rn(float2{b[0], b[1]});
    u.h[3] = __float22bfloat162_rn(float2{b[2], b[3]});
    return u.v;
}

__device__ __forceinline__ s16x4 cvt4(float a, float b, float c, float d) {
    union { __hip_bfloat162 h[2]; s16x4 v; } u;
    u.h[0] = __float22bfloat162_rn(float2{a, b});
    u.h[1] = __float22bfloat162_rn(float2{c, d});
    return u.v;
}

// async global->LDS, 16B per lane. LDS dest = wave-uniform base + lane*16.
__device__ __forceinline__ void gload_lds16(const void* g, void* l) {
    __builtin_amdgcn_global_load_lds(
        (const __attribute__((address_space(1))) unsigned int*)g,
        (__attribute__((address_space(3))) unsigned int*)l, 16, 0, 0);
}

// ---------------- fp32 -> bf16 weight fuse: Wqkv[3072][1024] = wq|wk|wv ----------------
__global__ void cvt_kernel(const float* __restrict__ wq, const float* __restrict__ wk,
                           const float* __restrict__ wv, ushort_t* __restrict__ Wqkv) {
    int tid = blockIdx.x * blockDim.x + threadIdx.x;   // 0..393215
    int z = tid >> 17;
    int off = (tid & 131071) * 8;
    const float* src = (z == 0) ? wq : (z == 1) ? wk : wv;
    f32x4 a = ((const f32x4*)(src + off))[0];
    f32x4 b = ((const f32x4*)(src + off))[1];
    *(bf16x8*)&Wqkv[(size_t)z * 1048576 + off] = cvt8(a, b);
}

// ---------------- fp32 -> bf16 activation convert: xb = bf16(x) ----------------
__global__ void cvt_x_kernel(const float* __restrict__ x, ushort_t* __restrict__ xb) {
    int tid = blockIdx.x * blockDim.x + threadIdx.x;   // 0..524287
    int off = tid * 8;
    f32x4 a = ((const f32x4*)(x + off))[0];
    f32x4 b = ((const f32x4*)(x + off))[1];
    *(bf16x8*)&xb[off] = cvt8(a, b);
}

// ---------------- RoPE tables ----------------
__global__ void rope_table_kernel(float* __restrict__ cos_t, float* __restrict__ sin_t) {
    int tid = blockIdx.x * blockDim.x + threadIdx.x;  // 0..65535
    int i = tid & 31, pos = tid >> 5;
    double freq = pow(10000.0, -(double)(2 * i) / 64.0);
    double ang = (double)pos * freq;
    cos_t[tid] = (float)cos(ang);
    sin_t[tid] = (float)sin(ang);
}

// ---------------- Fused QKV projection + RoPE + V-transpose ----------------
// (unchanged from round 8)
__global__ __launch_bounds__(256) void proj_qkv_kernel(
    const ushort_t* __restrict__ xb, const ushort_t* __restrict__ Wqkv,
    const float* __restrict__ cos_t, const float* __restrict__ sin_t,
    const int* __restrict__ tokpos,
    ushort_t* __restrict__ Qg, ushort_t* __restrict__ Kg, ushort_t* __restrict__ Vt)
{
    __shared__ __align__(16) short lA[2][128 * 32];   // 2 x 8 KB
    __shared__ __align__(16) short lB[2][128 * 32];   // 2 x 8 KB

    const int t = threadIdx.x;
    const int lane = t & 63;
    const int wid = t >> 6;
    const int quad = lane >> 4, l16 = lane & 15;
    const int mh = wid >> 1, nh = wid & 1;
    const int Mb = blockIdx.y * 128;
    const int NbG = blockIdx.x * 128;
    const int z = NbG >> 10;
    const int Nb = NbG & 1023;

    f32x4 acc[4][4] = {};

    auto stage = [&](int buf, int k0) {
        #pragma unroll
        for (int i = 0; i < 2; ++i) {
            int rbase = wid * 32 + i * 16;
            int row = rbase + (lane >> 2);
            int gch = (lane & 3) ^ ((lane >> 3) & 3);
            gload_lds16(xb + (size_t)(Mb + row) * DM + k0 + gch * 8, &lA[buf][rbase * 32]);
        }
        #pragma unroll
        for (int i = 0; i < 2; ++i) {
            int rbase = wid * 32 + i * 16;
            int row = rbase + (lane >> 2);
            int gch = (lane & 3) ^ ((lane >> 3) & 3);
            gload_lds16(Wqkv + (size_t)(NbG + row) * DM + k0 + gch * 8, &lB[buf][rbase * 32]);
        }
    };

    stage(0, 0);

    for (int kt = 0; kt < 32; ++kt) {
        const int cur = kt & 1;
        __syncthreads();
        if (kt < 31) stage(cur ^ 1, kt * 32 + 32);

        bf16x8 a[4], b[4];
        #pragma unroll
        for (int mt = 0; mt < 4; ++mt) {
            int row = mh * 64 + mt * 16 + l16;
            int slot = quad ^ ((l16 >> 1) & 3);
            a[mt] = *(const bf16x8*)&lA[cur][row * 32 + slot * 8];
        }
        #pragma unroll
        for (int nt = 0; nt < 4; ++nt) {
            int row = nh * 64 + nt * 16 + l16;
            int slot = quad ^ ((l16 >> 1) & 3);
            b[nt] = *(const bf16x8*)&lB[cur][row * 32 + slot * 8];
        }
        #pragma unroll
        for (int mt = 0; mt < 4; ++mt)
            #pragma unroll
            for (int nt = 0; nt < 4; ++nt)
                acc[mt][nt] = __builtin_amdgcn_mfma_f32_16x16x32_bf16(a[mt], b[nt], acc[mt][nt], 0, 0, 0);
    }

    const int bb = Mb >> 11;
    if (z == 2) {
        #pragma unroll
        for (int mt = 0; mt < 4; ++mt) {
            const int s0 = (Mb + mh * 64 + mt * 16 + quad * 4) & (SEQ - 1);
            #pragma unroll
            for (int nt = 0; nt < 4; ++nt) {
                int col = Nb + nh * 64 + nt * 16 + l16;
                int h = col >> 6, d = col & 63;
                s16x4 pk;
                #pragma unroll
                for (int r = 0; r < 4; ++r) pk[r] = f2bf(acc[mt][nt][r]);
                *(s16x4*)&Vt[((size_t)(bb * NH + h) * DKV + d) * SEQ + s0] = pk;
            }
        }
    } else {
        ushort_t* dst = (z == 0) ? Qg : Kg;
        #pragma unroll
        for (int mt = 0; mt < 4; ++mt) {
            #pragma unroll
            for (int nt = 0; nt < 4; ++nt) {
                #pragma unroll
                for (int r = 0; r < 4; ++r) {
                    int row = Mb + mh * 64 + mt * 16 + quad * 4 + r;
                    int s = row & (SEQ - 1);
                    int col = Nb + nh * 64 + nt * 16 + l16;
                    int h = col >> 6, d = col & 63;
                    float val = acc[mt][nt][r];
                    float part = __shfl_xor(val, 1, 64);
                    int pos = tokpos[s];
                    int i = d >> 1;
                    float c = cos_t[pos * 32 + i];
                    float sn = sin_t[pos * 32 + i];
                    val = (d & 1) ? (val * c + part * sn) : (val * c - part * sn);
                    dst[((size_t)(bb * NH + h) * SEQ + s) * DKV + d] = (ushort_t)f2bf(val);
                }
            }
        }
    }
}

// ---------------- Causal flash attention: 16 q-rows/wave, 2048 blocks ----------------
// grid (SEQ/32=64, 32), block 128 (2 waves x 16 q-rows). K/V tiles (32 k) shared
// via double-buffered gload LDS, 1 barrier/iter. m=0 softmax, S^T trick.
// 8 blocks/CU (16 waves) for latency hiding + fine-grained load balance.
__global__ __launch_bounds__(128, 8) void attn_kernel(
    const ushort_t* __restrict__ Q, const ushort_t* __restrict__ K,
    const ushort_t* __restrict__ Vt, ushort_t* __restrict__ O)
{
    __shared__ __align__(16) short lK[2][32 * 64];   // 8 KB
    __shared__ __align__(16) short lV[2][64 * 32];   // 8 KB
    __shared__ __align__(16) short lP[2][16 * PSTR]; // 2.5 KB, wave-private halves

    const int t = threadIdx.x;
    const int lane = t & 63;
    const int wid = t >> 6;                     // 0/1
    const int quad = lane >> 4, l16 = lane & 15;
    const int bh = blockIdx.y;
    const int qt = gridDim.x - 1 - blockIdx.x;  // longest blocks first
    const int q0 = qt * 32;
    const int q0w = q0 + wid * 16;
    const int nkt = qt + 1;

    const ushort_t* Qb = Q + (size_t)bh * SEQ * DKV;
    const ushort_t* Kb = K + (size_t)bh * SEQ * DKV;
    const ushort_t* Vtb = Vt + (size_t)bh * DKV * SEQ;

    auto stage = [&](int kb, int buf) {
        #pragma unroll
        for (int j = 0; j < 2; ++j) {           // K: 32 rows x 8 chunks, phys = gch^(row&7)
            int rbase = wid * 16 + j * 8;
            int row = rbase + (lane >> 3);
            int gch = (lane & 7) ^ (row & 7);
            gload_lds16(Kb + (size_t)(kb + row) * DKV + gch * 8, &lK[buf][rbase * 64]);
        }
        #pragma unroll
        for (int j = 0; j < 2; ++j) {           // V^T: 64 rows x 4 chunks, phys = gch^((row>>1)&3)
            int rbase = wid * 32 + j * 16;
            int row = rbase + (lane >> 2);
            int gch = (lane & 3) ^ ((lane >> 3) & 3);
            gload_lds16(Vtb + (size_t)row * SEQ + kb + gch * 8, &lV[buf][rbase * 32]);
        }
    };

    // Q fragments (B-operand of transposed QK): B[k=d][n=q], 16 q-rows
    bf16x8 bq[2];
    #pragma unroll
    for (int h = 0; h < 2; ++h)
        bq[h] = *(const bf16x8*)(Qb + (size_t)(q0w + l16) * DKV + h * 32 + quad * 8);

    f32x4 acc[4] = {};
    float ps = 0.f;
    short* myP = lP[wid];

    stage(0, 0);

    for (int kt = 0; kt < nkt; ++kt) {
        const int kbase = kt * 32;
        __syncthreads();                        // drains stage(kt)
        if (kt + 1 < nkt) stage(kbase + 32, (kt + 1) & 1);

        const short* bK = lK[kt & 1];
        const short* bV = lV[kt & 1];

        // K frags (A-operand of S^T): A[m=k][kc=d]
        bf16x8 ak[2][2];
        #pragma unroll
        for (int mt = 0; mt < 2; ++mt)
            #pragma unroll
            for (int h = 0; h < 2; ++h) {
                int row = mt * 16 + l16;
                int slot = (h * 4 + quad) ^ (row & 7);
                ak[mt][h] = *(const bf16x8*)&bK[row * 64 + slot * 8];
            }

        // S^T = K * Q^T : C row = k (mt*16+quad*4+r), col = q (l16)
        f32x4 st[2];
        #pragma unroll
        for (int mt = 0; mt < 2; ++mt) {
            f32x4 zz = {};
            zz = __builtin_amdgcn_mfma_f32_16x16x32_bf16(ak[mt][0], bq[0], zz, 0, 0, 0);
            zz = __builtin_amdgcn_mfma_f32_16x16x32_bf16(ak[mt][1], bq[1], zz, 0, 0, 0);
            st[mt] = zz;
        }

        // p = exp(s/8); element-wise mask only when the tile can cross this wave's diagonal.
        // NOTE: with 16-row waves the correct trigger is kbase+31 > q0w (not kbase >= q0w).
        if (kbase + 31 > q0w) {
            #pragma unroll
            for (int mt = 0; mt < 2; ++mt) {
                float pv[4];
                #pragma unroll
                for (int r = 0; r < 4; ++r) {
                    int k_abs = kbase + mt * 16 + quad * 4 + r;
                    int q_abs = q0w + l16;
                    pv[r] = (k_abs > q_abs) ? 0.f : __expf(st[mt][r] * 0.125f);
                    ps += pv[r];
                }
                *(s16x4*)&myP[l16 * PSTR + mt * 16 + quad * 4] = cvt4(pv[0], pv[1], pv[2], pv[3]);
            }
        } else {
            #pragma unroll
            for (int mt = 0; mt < 2; ++mt) {
                float pv[4];
                #pragma unroll
                for (int r = 0; r < 4; ++r) {
                    pv[r] = __expf(st[mt][r] * 0.125f);
                    ps += pv[r];
                }
                *(s16x4*)&myP[l16 * PSTR + mt * 16 + quad * 4] = cvt4(pv[0], pv[1], pv[2], pv[3]);
            }
        }

        // P back in A-layout: A[m=q=l16][k=quad*8+j]
        bf16x8 ap = *(const bf16x8*)&myP[l16 * PSTR + quad * 8];

        // O += P V  (B = V^T frags: B[k][n=d])
        #pragma unroll
        for (int d = 0; d < 4; ++d) {
            int row = d * 16 + l16;
            int slot = quad ^ ((l16 >> 1) & 3);
            bf16x8 bv = *(const bf16x8*)&bV[row * 32 + slot * 8];
            acc[d] = __builtin_amdgcn_mfma_f32_16x16x32_bf16(ap, bv, acc[d], 0, 0, 0);
        }
    }

    // epilogue (per wave): finish row-sum over quads for q=l16, bounce via wave-private LDS
    ps += __shfl_xor(ps, 16, 64);
    ps += __shfl_xor(ps, 32, 64);
    float* lLw = (float*)myP;   // P dead, reuse
    if (quad == 0) lLw[l16] = ps;
    const int bb = bh >> 4, h = bh & 15;
    f32x4 lv = *(const f32x4*)&lLw[quad * 4];
    f32x4 inv;
    #pragma unroll
    for (int r = 0; r < 4; ++r) inv[r] = 1.0f / lv[r];
    #pragma unroll
    for (int d = 0; d < 4; ++d)
        #pragma unroll
        for (int r = 0; r < 4; ++r) {
            int qrow = q0w + quad * 4 + r;
            int dd = d * 16 + l16;
            O[(size_t)(bb * SEQ + qrow) * DM + h * DKV + dd] = (ushort_t)f2bf(acc[d][r] * inv[r]);
        }
}

// ---------------- Output projection: out = AO * Wo^T ----------------
// (unchanged from round 8)
__global__ __launch_bounds__(256) void oproj_kernel(
    const ushort_t* __restrict__ A, const float* __restrict__ w, float* __restrict__ out)
{
    __shared__ __align__(16) short lA[2][64 * 32];     // 2 x 4 KB
    __shared__ __align__(16) float lBf[2][128 * 32];   // 2 x 16 KB

    const int t = threadIdx.x;
    const int lane = t & 63;
    const int wid = t >> 6;
    const int quad = lane >> 4, l16 = lane & 15;
    const int mh = wid >> 1, nh = wid & 1;   // wave tile: 32(M) x 64(N)
    const int Mb = blockIdx.y * 64;
    const int Nb = blockIdx.x * 128;

    f32x4 acc[2][4] = {};

    auto stage = [&](int buf, int k0) {
        {
            int rbase = wid * 16;
            int row = rbase + (lane >> 2);
            int gch = (lane & 3) ^ ((lane >> 3) & 3);
            gload_lds16(A + (size_t)(Mb + row) * DM + k0 + gch * 8, &lA[buf][rbase * 32]);
        }
        #pragma unroll
        for (int i = 0; i < 4; ++i) {
            int rbase = wid * 32 + i * 8;
            int row = rbase + (lane >> 3);
            int gch = (lane & 7) ^ (row & 7);
            gload_lds16(w + (size_t)(Nb + row) * DM + k0 + gch * 4, &lBf[buf][rbase * 32]);
        }
    };

    stage(0, 0);

    for (int kt = 0; kt < 32; ++kt) {
        const int cur = kt & 1;
        __syncthreads();
        if (kt < 31) stage(cur ^ 1, kt * 32 + 32);

        bf16x8 a[2], b[4];
        #pragma unroll
        for (int mt = 0; mt < 2; ++mt) {
            int row = mh * 32 + mt * 16 + l16;
            int slot = quad ^ ((l16 >> 1) & 3);
            a[mt] = *(const bf16x8*)&lA[cur][row * 32 + slot * 8];
        }
        #pragma unroll
        for (int nt = 0; nt < 4; ++nt) {
            int row = nh * 64 + nt * 16 + l16;
            int p0 = (2 * quad) ^ (row & 7);
            int p1 = (2 * quad + 1) ^ (row & 7);
            f32x4 q0 = *(const f32x4*)&lBf[cur][row * 32 + p0 * 4];
            f32x4 q1 = *(const f32x4*)&lBf[cur][row * 32 + p1 * 4];
            b[nt] = cvt8(q0, q1);
        }
        #pragma unroll
        for (int mt = 0; mt < 2; ++mt)
            #pragma unroll
            for (int nt = 0; nt < 4; ++nt)
                acc[mt][nt] = __builtin_amdgcn_mfma_f32_16x16x32_bf16(a[mt], b[nt], acc[mt][nt], 0, 0, 0);
    }

    #pragma unroll
    for (int mt = 0; mt < 2; ++mt)
        #pragma unroll
        for (int nt = 0; nt < 4; ++nt)
            #pragma unroll
            for (int r = 0; r < 4; ++r) {
                int row = Mb + mh * 32 + mt * 16 + quad * 4 + r;
                int col = Nb + nh * 64 + nt * 16 + l16;
                out[(size_t)row * DM + col] = acc[mt][nt][r];
            }
}

extern "C" void kernel_launch(void* const* d_in, const int* in_sizes, int n_in,
                              void* d_out, int out_size, void* d_ws, size_t ws_size,
                              hipStream_t stream) {
    const float* x  = (const float*)d_in[0];
    const float* wq = (const float*)d_in[1];
    const float* wk = (const float*)d_in[2];
    const float* wv = (const float*)d_in[3];
    const float* wo = (const float*)d_in[4];
    const int* tokpos = (const int*)d_in[5];
    float* out = (float*)d_out;

    // Workspace (32 MB; AO aliases cos/sin/Wqkv which are dead after proj).
    // xb (bf16 copy of x, 8 MB) lives in d_out — dead until oproj writes it.
    char* ws = (char*)d_ws;
    float* cos_t    = (float*)ws;                          // 256 KB
    float* sin_t    = (float*)(ws + 256 * 1024);           // 256 KB
    ushort_t* Wqkv  = (ushort_t*)(ws + 512 * 1024);        // 6 MB
    ushort_t* AO    = (ushort_t*)ws;                       // 8 MB (aliases the above)
    ushort_t* Qg    = (ushort_t*)(ws + (size_t)8  * 1024 * 1024);  // 8 MB
    ushort_t* Kg    = (ushort_t*)(ws + (size_t)16 * 1024 * 1024);  // 8 MB
    ushort_t* Vt    = (ushort_t*)(ws + (size_t)24 * 1024 * 1024);  // 8 MB
    ushort_t* xb    = (ushort_t*)d_out;                    // 8 MB scratch in out-buffer

    cvt_kernel<<<1536, 256, 0, stream>>>(wq, wk, wv, Wqkv);
    cvt_x_kernel<<<2048, 256, 0, stream>>>(x, xb);
    rope_table_kernel<<<256, 256, 0, stream>>>(cos_t, sin_t);
    proj_qkv_kernel<<<dim3(3 * DM / 128, MTOT / 128), 256, 0, stream>>>(
        xb, Wqkv, cos_t, sin_t, tokpos, Qg, Kg, Vt);
    attn_kernel<<<dim3(SEQ / 32, 32), 128, 0, stream>>>(Qg, Kg, Vt, AO);
    oproj_kernel<<<dim3(DM / 128, MTOT / 64), 256, 0, stream>>>(AO, wo, out);
}

// Round 10
// 238.042 us; speedup vs baseline: 1.0265x; 1.0265x over previous
//
#include <hip/hip_runtime.h>
#include <hip/hip_bf16.h>
#include <math.h>

#define SEQ 2048
#define DM 1024
#define NH 16
#define DKV 64
#define MTOT 4096   /* BATCH*SEQ */
#define PSTR 40     /* P-tile LDS row stride in shorts */

typedef __attribute__((ext_vector_type(8))) short bf16x8;
typedef __attribute__((ext_vector_type(4))) short s16x4;
typedef __attribute__((ext_vector_type(4))) float f32x4;
typedef unsigned short ushort_t;

__device__ __forceinline__ short f2bf(float f) {
    union { float f; unsigned u; } v; v.f = f;
    unsigned r = v.u + 0x7fffu + ((v.u >> 16) & 1u);
    return (short)(r >> 16);
}

__device__ __forceinline__ bf16x8 cvt8(f32x4 a, f32x4 b) {
    union { __hip_bfloat162 h[4]; bf16x8 v; } u;
    u.h[0] = __float22bfloat162_rn(float2{a[0], a[1]});
    u.h[1] = __float22bfloat162_rn(float2{a[2], a[3]});
    u.h[2] = __float22bfloat162_rn(float2{b[0], b[1]});
    u.h[3] = __float22bfloat162_rn(float2{b[2], b[3]});
    return u.v;
}

__device__ __forceinline__ s16x4 cvt4(float a, float b, float c, float d) {
    union { __hip_bfloat162 h[2]; s16x4 v; } u;
    u.h[0] = __float22bfloat162_rn(float2{a, b});
    u.h[1] = __float22bfloat162_rn(float2{c, d});
    return u.v;
}

// async global->LDS, 16B per lane. LDS dest = wave-uniform base + lane*16.
__device__ __forceinline__ void gload_lds16(const void* g, void* l) {
    __builtin_amdgcn_global_load_lds(
        (const __attribute__((address_space(1))) unsigned int*)g,
        (__attribute__((address_space(3))) unsigned int*)l, 16, 0, 0);
}

// ---------------- fp32 -> bf16 weight fuse: Wqkv[3072][1024] = wq|wk|wv ----------------
__global__ void cvt_kernel(const float* __restrict__ wq, const float* __restrict__ wk,
                           const float* __restrict__ wv, ushort_t* __restrict__ Wqkv) {
    int tid = blockIdx.x * blockDim.x + threadIdx.x;   // 0..393215
    int z = tid >> 17;
    int off = (tid & 131071) * 8;
    const float* src = (z == 0) ? wq : (z == 1) ? wk : wv;
    f32x4 a = ((const f32x4*)(src + off))[0];
    f32x4 b = ((const f32x4*)(src + off))[1];
    *(bf16x8*)&Wqkv[(size_t)z * 1048576 + off] = cvt8(a, b);
}

// ---------------- generic fp32 -> bf16 convert (x, wo) ----------------
__global__ void cvt_f2b_kernel(const float* __restrict__ src, ushort_t* __restrict__ dst) {
    int tid = blockIdx.x * blockDim.x + threadIdx.x;
    int off = tid * 8;
    f32x4 a = ((const f32x4*)(src + off))[0];
    f32x4 b = ((const f32x4*)(src + off))[1];
    *(bf16x8*)&dst[off] = cvt8(a, b);
}

// ---------------- RoPE tables ----------------
__global__ void rope_table_kernel(float* __restrict__ cos_t, float* __restrict__ sin_t) {
    int tid = blockIdx.x * blockDim.x + threadIdx.x;  // 0..65535
    int i = tid & 31, pos = tid >> 5;
    double freq = pow(10000.0, -(double)(2 * i) / 64.0);
    double ang = (double)pos * freq;
    cos_t[tid] = (float)cos(ang);
    sin_t[tid] = (float)sin(ang);
}

// ---------------- Fused QKV projection + RoPE + V-transpose ----------------
// C = Xb * Wqkv^T, both bf16. Tile 128(M) x 64(N), BK=32, dbuf gload LDS,
// 1 barrier/iter. grid (48, 32) = 1536 blocks (~6/CU). Wave tile 64x32.
__global__ __launch_bounds__(256) void proj_qkv_kernel(
    const ushort_t* __restrict__ xb, const ushort_t* __restrict__ Wqkv,
    const float* __restrict__ cos_t, const float* __restrict__ sin_t,
    const int* __restrict__ tokpos,
    ushort_t* __restrict__ Qg, ushort_t* __restrict__ Kg, ushort_t* __restrict__ Vt)
{
    __shared__ __align__(16) short lA[2][128 * 32];   // 2 x 8 KB
    __shared__ __align__(16) short lB[2][64 * 32];    // 2 x 4 KB

    const int t = threadIdx.x;
    const int lane = t & 63;
    const int wid = t >> 6;
    const int quad = lane >> 4, l16 = lane & 15;
    const int mh = wid >> 1, nh = wid & 1;   // wave: 64(M) x 32(N)
    const int Mb = blockIdx.y * 128;
    const int NbG = blockIdx.x * 64;
    const int z = NbG >> 10;
    const int Nb = NbG & 1023;

    f32x4 acc[4][2] = {};

    auto stage = [&](int buf, int k0) {
        #pragma unroll
        for (int i = 0; i < 2; ++i) {   // A: 32 rows per wave
            int rbase = wid * 32 + i * 16;
            int row = rbase + (lane >> 2);
            int gch = (lane & 3) ^ ((lane >> 3) & 3);
            gload_lds16(xb + (size_t)(Mb + row) * DM + k0 + gch * 8, &lA[buf][rbase * 32]);
        }
        {   // B: 16 rows per wave
            int rbase = wid * 16;
            int row = rbase + (lane >> 2);
            int gch = (lane & 3) ^ ((lane >> 3) & 3);
            gload_lds16(Wqkv + (size_t)(NbG + row) * DM + k0 + gch * 8, &lB[buf][rbase * 32]);
        }
    };

    stage(0, 0);

    for (int kt = 0; kt < 32; ++kt) {
        const int cur = kt & 1;
        __syncthreads();
        if (kt < 31) stage(cur ^ 1, kt * 32 + 32);

        bf16x8 a[4], b[2];
        #pragma unroll
        for (int mt = 0; mt < 4; ++mt) {
            int row = mh * 64 + mt * 16 + l16;
            int slot = quad ^ ((l16 >> 1) & 3);
            a[mt] = *(const bf16x8*)&lA[cur][row * 32 + slot * 8];
        }
        #pragma unroll
        for (int nt = 0; nt < 2; ++nt) {
            int row = nh * 32 + nt * 16 + l16;
            int slot = quad ^ ((l16 >> 1) & 3);
            b[nt] = *(const bf16x8*)&lB[cur][row * 32 + slot * 8];
        }
        #pragma unroll
        for (int mt = 0; mt < 4; ++mt)
            #pragma unroll
            for (int nt = 0; nt < 2; ++nt)
                acc[mt][nt] = __builtin_amdgcn_mfma_f32_16x16x32_bf16(a[mt], b[nt], acc[mt][nt], 0, 0, 0);
    }

    const int bb = Mb >> 11;
    if (z == 2) {
        #pragma unroll
        for (int mt = 0; mt < 4; ++mt) {
            const int s0 = (Mb + mh * 64 + mt * 16 + quad * 4) & (SEQ - 1);
            #pragma unroll
            for (int nt = 0; nt < 2; ++nt) {
                int col = Nb + nh * 32 + nt * 16 + l16;
                int h = col >> 6, d = col & 63;
                s16x4 pk;
                #pragma unroll
                for (int r = 0; r < 4; ++r) pk[r] = f2bf(acc[mt][nt][r]);
                *(s16x4*)&Vt[((size_t)(bb * NH + h) * DKV + d) * SEQ + s0] = pk;
            }
        }
    } else {
        ushort_t* dst = (z == 0) ? Qg : Kg;
        #pragma unroll
        for (int mt = 0; mt < 4; ++mt) {
            #pragma unroll
            for (int nt = 0; nt < 2; ++nt) {
                #pragma unroll
                for (int r = 0; r < 4; ++r) {
                    int row = Mb + mh * 64 + mt * 16 + quad * 4 + r;
                    int s = row & (SEQ - 1);
                    int col = Nb + nh * 32 + nt * 16 + l16;
                    int h = col >> 6, d = col & 63;
                    float val = acc[mt][nt][r];
                    float part = __shfl_xor(val, 1, 64);
                    int pos = tokpos[s];
                    int i = d >> 1;
                    float c = cos_t[pos * 32 + i];
                    float sn = sin_t[pos * 32 + i];
                    val = (d & 1) ? (val * c + part * sn) : (val * c - part * sn);
                    dst[((size_t)(bb * NH + h) * SEQ + s) * DKV + d] = (ushort_t)f2bf(val);
                }
            }
        }
    }
}

// ---------------- Causal flash attention: 16 q-rows/wave, 2048 blocks ----------------
// (unchanged from round 9)
__global__ __launch_bounds__(128, 8) void attn_kernel(
    const ushort_t* __restrict__ Q, const ushort_t* __restrict__ K,
    const ushort_t* __restrict__ Vt, ushort_t* __restrict__ O)
{
    __shared__ __align__(16) short lK[2][32 * 64];   // 8 KB
    __shared__ __align__(16) short lV[2][64 * 32];   // 8 KB
    __shared__ __align__(16) short lP[2][16 * PSTR]; // 2.5 KB, wave-private halves

    const int t = threadIdx.x;
    const int lane = t & 63;
    const int wid = t >> 6;                     // 0/1
    const int quad = lane >> 4, l16 = lane & 15;
    const int bh = blockIdx.y;
    const int qt = gridDim.x - 1 - blockIdx.x;  // longest blocks first
    const int q0 = qt * 32;
    const int q0w = q0 + wid * 16;
    const int nkt = qt + 1;

    const ushort_t* Qb = Q + (size_t)bh * SEQ * DKV;
    const ushort_t* Kb = K + (size_t)bh * SEQ * DKV;
    const ushort_t* Vtb = Vt + (size_t)bh * DKV * SEQ;

    auto stage = [&](int kb, int buf) {
        #pragma unroll
        for (int j = 0; j < 2; ++j) {           // K: 32 rows x 8 chunks, phys = gch^(row&7)
            int rbase = wid * 16 + j * 8;
            int row = rbase + (lane >> 3);
            int gch = (lane & 7) ^ (row & 7);
            gload_lds16(Kb + (size_t)(kb + row) * DKV + gch * 8, &lK[buf][rbase * 64]);
        }
        #pragma unroll
        for (int j = 0; j < 2; ++j) {           // V^T: 64 rows x 4 chunks, phys = gch^((row>>1)&3)
            int rbase = wid * 32 + j * 16;
            int row = rbase + (lane >> 2);
            int gch = (lane & 3) ^ ((lane >> 3) & 3);
            gload_lds16(Vtb + (size_t)row * SEQ + kb + gch * 8, &lV[buf][rbase * 32]);
        }
    };

    // Q fragments (B-operand of transposed QK): B[k=d][n=q], 16 q-rows
    bf16x8 bq[2];
    #pragma unroll
    for (int h = 0; h < 2; ++h)
        bq[h] = *(const bf16x8*)(Qb + (size_t)(q0w + l16) * DKV + h * 32 + quad * 8);

    f32x4 acc[4] = {};
    float ps = 0.f;
    short* myP = lP[wid];

    stage(0, 0);

    for (int kt = 0; kt < nkt; ++kt) {
        const int kbase = kt * 32;
        __syncthreads();                        // drains stage(kt)
        if (kt + 1 < nkt) stage(kbase + 32, (kt + 1) & 1);

        const short* bK = lK[kt & 1];
        const short* bV = lV[kt & 1];

        // K frags (A-operand of S^T): A[m=k][kc=d]
        bf16x8 ak[2][2];
        #pragma unroll
        for (int mt = 0; mt < 2; ++mt)
            #pragma unroll
            for (int h = 0; h < 2; ++h) {
                int row = mt * 16 + l16;
                int slot = (h * 4 + quad) ^ (row & 7);
                ak[mt][h] = *(const bf16x8*)&bK[row * 64 + slot * 8];
            }

        // S^T = K * Q^T : C row = k (mt*16+quad*4+r), col = q (l16)
        f32x4 st[2];
        #pragma unroll
        for (int mt = 0; mt < 2; ++mt) {
            f32x4 zz = {};
            zz = __builtin_amdgcn_mfma_f32_16x16x32_bf16(ak[mt][0], bq[0], zz, 0, 0, 0);
            zz = __builtin_amdgcn_mfma_f32_16x16x32_bf16(ak[mt][1], bq[1], zz, 0, 0, 0);
            st[mt] = zz;
        }

        // p = exp(s/8); element-wise mask only when the tile can cross this wave's diagonal.
        if (kbase + 31 > q0w) {
            #pragma unroll
            for (int mt = 0; mt < 2; ++mt) {
                float pv[4];
                #pragma unroll
                for (int r = 0; r < 4; ++r) {
                    int k_abs = kbase + mt * 16 + quad * 4 + r;
                    int q_abs = q0w + l16;
                    pv[r] = (k_abs > q_abs) ? 0.f : __expf(st[mt][r] * 0.125f);
                    ps += pv[r];
                }
                *(s16x4*)&myP[l16 * PSTR + mt * 16 + quad * 4] = cvt4(pv[0], pv[1], pv[2], pv[3]);
            }
        } else {
            #pragma unroll
            for (int mt = 0; mt < 2; ++mt) {
                float pv[4];
                #pragma unroll
                for (int r = 0; r < 4; ++r) {
                    pv[r] = __expf(st[mt][r] * 0.125f);
                    ps += pv[r];
                }
                *(s16x4*)&myP[l16 * PSTR + mt * 16 + quad * 4] = cvt4(pv[0], pv[1], pv[2], pv[3]);
            }
        }

        // P back in A-layout: A[m=q=l16][k=quad*8+j]
        bf16x8 ap = *(const bf16x8*)&myP[l16 * PSTR + quad * 8];

        // O += P V  (B = V^T frags: B[k][n=d])
        #pragma unroll
        for (int d = 0; d < 4; ++d) {
            int row = d * 16 + l16;
            int slot = quad ^ ((l16 >> 1) & 3);
            bf16x8 bv = *(const bf16x8*)&bV[row * 32 + slot * 8];
            acc[d] = __builtin_amdgcn_mfma_f32_16x16x32_bf16(ap, bv, acc[d], 0, 0, 0);
        }
    }

    // epilogue (per wave)
    ps += __shfl_xor(ps, 16, 64);
    ps += __shfl_xor(ps, 32, 64);
    float* lLw = (float*)myP;   // P dead, reuse
    if (quad == 0) lLw[l16] = ps;
    const int bb = bh >> 4, h = bh & 15;
    f32x4 lv = *(const f32x4*)&lLw[quad * 4];
    f32x4 inv;
    #pragma unroll
    for (int r = 0; r < 4; ++r) inv[r] = 1.0f / lv[r];
    #pragma unroll
    for (int d = 0; d < 4; ++d)
        #pragma unroll
        for (int r = 0; r < 4; ++r) {
            int qrow = q0w + quad * 4 + r;
            int dd = d * 16 + l16;
            O[(size_t)(bb * SEQ + qrow) * DM + h * DKV + dd] = (ushort_t)f2bf(acc[d][r] * inv[r]);
        }
}

// ---------------- Output projection: out = AO * Wob^T (all bf16) ----------------
// Tile 64x64, BK=32, dbuf gload LDS, grid (16, 64) = 1024 blocks (~4/CU).
// Wave tile 32x32 (2x2 MFMA).
__global__ __launch_bounds__(256) void oproj_kernel(
    const ushort_t* __restrict__ A, const ushort_t* __restrict__ B, float* __restrict__ out)
{
    __shared__ __align__(16) short lA[2][64 * 32];   // 2 x 4 KB
    __shared__ __align__(16) short lB[2][64 * 32];   // 2 x 4 KB

    const int t = threadIdx.x;
    const int lane = t & 63;
    const int wid = t >> 6;
    const int quad = lane >> 4, l16 = lane & 15;
    const int mh = wid >> 1, nh = wid & 1;   // wave: 32(M) x 32(N)
    const int Mb = blockIdx.y * 64;
    const int Nb = blockIdx.x * 64;

    f32x4 acc[2][2] = {};

    auto stage = [&](int buf, int k0) {
        {   // A: 16 rows per wave
            int rbase = wid * 16;
            int row = rbase + (lane >> 2);
            int gch = (lane & 3) ^ ((lane >> 3) & 3);
            gload_lds16(A + (size_t)(Mb + row) * DM + k0 + gch * 8, &lA[buf][rbase * 32]);
        }
        {   // B: 16 rows per wave
            int rbase = wid * 16;
            int row = rbase + (lane >> 2);
            int gch = (lane & 3) ^ ((lane >> 3) & 3);
            gload_lds16(B + (size_t)(Nb + row) * DM + k0 + gch * 8, &lB[buf][rbase * 32]);
        }
    };

    stage(0, 0);

    for (int kt = 0; kt < 32; ++kt) {
        const int cur = kt & 1;
        __syncthreads();
        if (kt < 31) stage(cur ^ 1, kt * 32 + 32);

        bf16x8 a[2], b[2];
        #pragma unroll
        for (int mt = 0; mt < 2; ++mt) {
            int row = mh * 32 + mt * 16 + l16;
            int slot = quad ^ ((l16 >> 1) & 3);
            a[mt] = *(const bf16x8*)&lA[cur][row * 32 + slot * 8];
        }
        #pragma unroll
        for (int nt = 0; nt < 2; ++nt) {
            int row = nh * 32 + nt * 16 + l16;
            int slot = quad ^ ((l16 >> 1) & 3);
            b[nt] = *(const bf16x8*)&lB[cur][row * 32 + slot * 8];
        }
        #pragma unroll
        for (int mt = 0; mt < 2; ++mt)
            #pragma unroll
            for (int nt = 0; nt < 2; ++nt)
                acc[mt][nt] = __builtin_amdgcn_mfma_f32_16x16x32_bf16(a[mt], b[nt], acc[mt][nt], 0, 0, 0);
    }

    #pragma unroll
    for (int mt = 0; mt < 2; ++mt)
        #pragma unroll
        for (int nt = 0; nt < 2; ++nt)
            #pragma unroll
            for (int r = 0; r < 4; ++r) {
                int row = Mb + mh * 32 + mt * 16 + quad * 4 + r;
                int col = Nb + nh * 32 + nt * 16 + l16;
                out[(size_t)row * DM + col] = acc[mt][nt][r];
            }
}

extern "C" void kernel_launch(void* const* d_in, const int* in_sizes, int n_in,
                              void* d_out, int out_size, void* d_ws, size_t ws_size,
                              hipStream_t stream) {
    const float* x  = (const float*)d_in[0];
    const float* wq = (const float*)d_in[1];
    const float* wk = (const float*)d_in[2];
    const float* wv = (const float*)d_in[3];
    const float* wo = (const float*)d_in[4];
    const int* tokpos = (const int*)d_in[5];
    float* out = (float*)d_out;

    // Workspace (32 MB):
    //  [0:8M)   cos/sin/Wqkv (live through proj) -> AO (written by attn)
    //  [8:16M)  Qg (live through attn)           -> Wob (written by cvt after attn)
    //  [16:24M) Kg
    //  [24:32M) Vt
    // xb (bf16 x, 8 MB) lives in d_out[0:8M) — dead until oproj writes out.
    char* ws = (char*)d_ws;
    float* cos_t    = (float*)ws;                          // 256 KB
    float* sin_t    = (float*)(ws + 256 * 1024);           // 256 KB
    ushort_t* Wqkv  = (ushort_t*)(ws + 512 * 1024);        // 6 MB
    ushort_t* AO    = (ushort_t*)ws;                       // 8 MB (aliases the above)
    ushort_t* Qg    = (ushort_t*)(ws + (size_t)8  * 1024 * 1024);  // 8 MB
    ushort_t* Kg    = (ushort_t*)(ws + (size_t)16 * 1024 * 1024);  // 8 MB
    ushort_t* Vt    = (ushort_t*)(ws + (size_t)24 * 1024 * 1024);  // 8 MB
    ushort_t* Wob   = Qg;                                  // 2 MB, after attn
    ushort_t* xb    = (ushort_t*)d_out;                    // 8 MB scratch in out-buffer

    cvt_kernel<<<1536, 256, 0, stream>>>(wq, wk, wv, Wqkv);
    cvt_f2b_kernel<<<2048, 256, 0, stream>>>(x, xb);
    rope_table_kernel<<<256, 256, 0, stream>>>(cos_t, sin_t);
    proj_qkv_kernel<<<dim3(3 * DM / 64, MTOT / 128), 256, 0, stream>>>(
        xb, Wqkv, cos_t, sin_t, tokpos, Qg, Kg, Vt);
    attn_kernel<<<dim3(SEQ / 32, 32), 128, 0, stream>>>(Qg, Kg, Vt, AO);
    cvt_f2b_kernel<<<512, 256, 0, stream>>>(wo, Wob);   // Qg dead; oproj B operand
    oproj_kernel<<<dim3(DM / 64, MTOT / 64), 256, 0, stream>>>(AO, Wob, out);
}